// Round 11
// baseline (298.020 us; speedup 1.0000x reference)
//
#include <hip/hip_runtime.h>
#include <hip/hip_bf16.h>
#include <hip/hip_cooperative_groups.h>
#include <cstdint>
#include <cstddef>

namespace cg = cooperative_groups;

#define U   32
#define DM  2560
#define DI  5120
#define DS  16
#define RNK 160
#define XD  192   // RNK + 2*DS
#define KC1 20    // K1 k-slices (SLAB 128)
#define KC4 80    // K4 k-slices (SLAB 64)

typedef __attribute__((ext_vector_type(8)))  short bf16x8;
typedef __attribute__((ext_vector_type(16))) float f32x16;

__device__ __forceinline__ unsigned int pkbf(float a, float b) {
  __hip_bfloat162 h = __float22bfloat162_rn(make_float2(a, b));
  union { __hip_bfloat162 h; unsigned int u; } v; v.h = h; return v.u;
}
__device__ __forceinline__ unsigned short f2bfu(float f) {
  __hip_bfloat16 h = __float2bfloat16(f);
  union { __hip_bfloat16 h; unsigned short u; } v; v.h = h; return v.u;
}
__device__ __forceinline__ float bf2f(unsigned int s) {
  union { float f; unsigned int u; } v; v.u = s << 16; return v.f;
}

// async global->LDS DMA, 16B per lane; lds dest = wave-uniform base + lane*16
__device__ __forceinline__ void gl_lds16(const float* g, float* l) {
  __builtin_amdgcn_global_load_lds(
      (const __attribute__((address_space(1))) unsigned int*)g,
      (__attribute__((address_space(3))) unsigned int*)l,
      16, 0, 0);
}

// ---------------------------------------------------------------------------
// MFMA skinny GEMM (round-10 v7, unchanged): counted-vmcnt double-buffered
// global_load_lds pipeline; bf16 partials part[z][kcb][32][LDW].
// ---------------------------------------------------------------------------
template<int LDW, int SLAB>
__global__ __launch_bounds__(256, 3) void skinny_dma(
    const float* __restrict__ A, int lda,
    const float* __restrict__ W0, const float* __restrict__ W1,
    unsigned short* __restrict__ part)
{
  constexpr int NS = SLAB / 16;                 // >= 2
  __shared__ float        wbuf[2][16][256];     // 32 KB fp32 W tiles (dbuf)
  __shared__ unsigned int albuf[NS][64][4];     // A frags bf16, 1KB per k-step

  const int tid  = threadIdx.x;
  const int lane = tid & 63, w = tid >> 6;
  const int kcb  = blockIdx.y, z = blockIdx.z;
  const int k0   = kcb * SLAB;
  const float* __restrict__ W = z ? W1 : W0;
  const int col0 = blockIdx.x * 256;

  for (int i = tid; i < U * (SLAB / 2); i += 256) {
    const int u  = i / (SLAB / 2);
    const int kp = i - u * (SLAB / 2);
    const int k  = 2 * kp;
    const float2 v = *(const float2*)&A[(size_t)u * lda + k0 + k];
    albuf[k >> 4][u + U * ((k >> 3) & 1)][(k >> 1) & 3] = pkbf(v.x, v.y);
  }
  __syncthreads();    // albuf visible; vmcnt baseline = 0

  const int cl = lane & 31, half = lane >> 5;
  const float* wsrc = W + ((size_t)k0 + w * 4) * LDW + col0 + lane * 4;

#pragma unroll
  for (int i = 0; i < 4; ++i)
    gl_lds16(wsrc + (size_t)i * LDW, &wbuf[0][w * 4 + i][0]);
#pragma unroll
  for (int i = 0; i < 4; ++i)
    gl_lds16(wsrc + (size_t)(16 + i) * LDW, &wbuf[1][w * 4 + i][0]);

  f32x16 acc0{}, acc1{};

#pragma unroll 1
  for (int s = 0; s < NS; ++s) {
    const int buf = s & 1;
    if (s + 1 < NS) { asm volatile("s_waitcnt vmcnt(4)" ::: "memory"); }
    else            { asm volatile("s_waitcnt vmcnt(0)" ::: "memory"); }
    __builtin_amdgcn_s_barrier();

    bf16x8 af = *(const bf16x8*)&albuf[s][lane][0];
#pragma unroll
    for (int f = 0; f < 2; ++f) {
      const int col = w * 64 + f * 32 + cl;
      float r0 = wbuf[buf][half * 8 + 0][col];
      float r1 = wbuf[buf][half * 8 + 1][col];
      float r2 = wbuf[buf][half * 8 + 2][col];
      float r3 = wbuf[buf][half * 8 + 3][col];
      float r4 = wbuf[buf][half * 8 + 4][col];
      float r5 = wbuf[buf][half * 8 + 5][col];
      float r6 = wbuf[buf][half * 8 + 6][col];
      float r7 = wbuf[buf][half * 8 + 7][col];
      union { bf16x8 v; unsigned int d[4]; } bu;
      bu.d[0] = pkbf(r0, r1); bu.d[1] = pkbf(r2, r3);
      bu.d[2] = pkbf(r4, r5); bu.d[3] = pkbf(r6, r7);
      if (f == 0) acc0 = __builtin_amdgcn_mfma_f32_32x32x16_bf16(af, bu.v, acc0, 0, 0, 0);
      else        acc1 = __builtin_amdgcn_mfma_f32_32x32x16_bf16(af, bu.v, acc1, 0, 0, 0);
    }

    asm volatile("" ::: "memory");
    __builtin_amdgcn_s_barrier();
    asm volatile("" ::: "memory");

    if (s + 2 < NS) {
      const float* src = wsrc + (size_t)(s + 2) * 16 * LDW;
#pragma unroll
      for (int i = 0; i < 4; ++i)
        gl_lds16(src + (size_t)i * LDW, &wbuf[buf][w * 4 + i][0]);
    }
  }

  unsigned short* po = part + (size_t)(z * gridDim.y + kcb) * U * LDW + col0;
#pragma unroll
  for (int f = 0; f < 2; ++f) {
    const f32x16& a = f ? acc1 : acc0;
    const int gc = w * 64 + f * 32 + cl;
#pragma unroll
    for (int r = 0; r < 16; ++r) {
      const int m = (r & 3) + 8 * (r >> 2) + 4 * half;
      po[(size_t)m * LDW + gc] = f2bfu(a[r]);
    }
  }
}

// ---------------------------------------------------------------------------
// Shared device bodies for the middle chain (used by fused + fallback).
// ---------------------------------------------------------------------------
__device__ __forceinline__ void k2a_body(
    int t,
    const unsigned short* __restrict__ part,
    const float* __restrict__ cs1, const float* __restrict__ cs2,
    const float* __restrict__ cs3,
    const float* __restrict__ cw,  const float* __restrict__ cb,
    float* __restrict__ c_ws, float* __restrict__ res_ws)
{
  const int i = 2 * t;
  const int u = i / DI, d = i - u * DI;
  float xs0 = 0.f, xs1 = 0.f, rs0 = 0.f, rs1 = 0.f;
#pragma unroll 4
  for (int kc = 0; kc < KC1; ++kc) {
    unsigned int a = *(const unsigned int*)&part[((size_t)kc * U + u) * DI + d];
    unsigned int b = *(const unsigned int*)&part[((size_t)(KC1 + kc) * U + u) * DI + d];
    xs0 += bf2f(a & 0xffffu); xs1 += bf2f(a >> 16);
    rs0 += bf2f(b & 0xffffu); rs1 += bf2f(b >> 16);
  }
  const float2 s1 = *(const float2*)&cs1[i];
  const float2 s2 = *(const float2*)&cs2[i];
  const float2 s3 = *(const float2*)&cs3[i];
  const float2 w0 = *(const float2*)&cw[d];
  const float2 w1 = *(const float2*)&cw[DI + d];
  const float2 w2 = *(const float2*)&cw[2 * DI + d];
  const float2 w3 = *(const float2*)&cw[3 * DI + d];
  const float2 bb = *(const float2*)&cb[d];
  float c0 = s1.x * w0.x + s2.x * w1.x + s3.x * w2.x + xs0 * w3.x + bb.x;
  float c1 = s1.y * w0.y + s2.y * w1.y + s3.y * w2.y + xs1 * w3.y + bb.y;
  c0 = c0 / (1.f + __expf(-c0));
  c1 = c1 / (1.f + __expf(-c1));
  *(float2*)&c_ws[i]   = make_float2(c0, c1);
  *(float2*)&res_ws[i] = make_float2(rs0, rs1);
}

union MidSh { float ct[U][80]; float xt[U][160]; float red[4][64][33]; };

__device__ __forceinline__ void k2b_body(
    MidSh& sh, int bx, int by, int tid,
    const float* __restrict__ c_ws, const float* __restrict__ xpw,
    float* __restrict__ x_dbl)
{
  const int k0 = by * 80;
  for (int i4 = tid; i4 < U * 20; i4 += 256) {
    int u = i4 / 20, k4 = i4 - u * 20;
    *(float4*)&sh.ct[u][k4 * 4] = *(const float4*)&c_ws[u * DI + k0 + k4 * 4];
  }
  __syncthreads();

  const int c = tid & 63, s = tid >> 6;
  const int col = bx * 64 + c;              // 0..191
  const float* Wp = xpw + (size_t)(k0 + s * 20) * XD + col;

  float acc[U];
#pragma unroll
  for (int u = 0; u < U; ++u) acc[u] = 0.f;

  for (int kk = 0; kk < 20; kk += 4) {
    float w0 = Wp[(size_t)(kk + 0) * XD];
    float w1 = Wp[(size_t)(kk + 1) * XD];
    float w2 = Wp[(size_t)(kk + 2) * XD];
    float w3 = Wp[(size_t)(kk + 3) * XD];
#pragma unroll
    for (int u = 0; u < U; ++u) {
      float4 cv = *(const float4*)&sh.ct[u][s * 20 + kk];
      acc[u] = fmaf(cv.x, w0, acc[u]);
      acc[u] = fmaf(cv.y, w1, acc[u]);
      acc[u] = fmaf(cv.z, w2, acc[u]);
      acc[u] = fmaf(cv.w, w3, acc[u]);
    }
  }

  __syncthreads();
#pragma unroll
  for (int u = 0; u < U; ++u) sh.red[s][c][u] = acc[u];
  __syncthreads();

  for (int p = tid; p < 64 * U; p += 256) {
    int cc = p & 63, u = p >> 6;
    float v = sh.red[0][cc][u] + sh.red[1][cc][u] + sh.red[2][cc][u] + sh.red[3][cc][u];
    atomicAdd(&x_dbl[u * XD + bx * 64 + cc], v);
  }
}

__device__ __forceinline__ void k3a_body(
    MidSh& sh, int bx, int tid,
    const float* __restrict__ x_dbl,
    const float* __restrict__ dpw, const float* __restrict__ dpb,
    float* __restrict__ dt_ws)
{
  for (int i4 = tid; i4 < U * 40; i4 += 256) {
    int u = i4 / 40, r4 = i4 - u * 40;
    *(float4*)&sh.xt[u][r4 * 4] = *(const float4*)&x_dbl[u * XD + r4 * 4];
  }
  __syncthreads();

  const int c = tid & 63, s = tid >> 6;
  const int d = bx * 64 + c;
  const float* Wp = dpw + (size_t)(s * 40) * DI + d;

  float acc[U];
#pragma unroll
  for (int u = 0; u < U; ++u) acc[u] = 0.f;

  for (int rr = 0; rr < 40; rr += 4) {
    float w0 = Wp[(size_t)(rr + 0) * DI];
    float w1 = Wp[(size_t)(rr + 1) * DI];
    float w2 = Wp[(size_t)(rr + 2) * DI];
    float w3 = Wp[(size_t)(rr + 3) * DI];
#pragma unroll
    for (int u = 0; u < U; ++u) {
      float4 xv = *(const float4*)&sh.xt[u][s * 40 + rr];
      acc[u] = fmaf(xv.x, w0, acc[u]);
      acc[u] = fmaf(xv.y, w1, acc[u]);
      acc[u] = fmaf(xv.z, w2, acc[u]);
      acc[u] = fmaf(xv.w, w3, acc[u]);
    }
  }

  __syncthreads();
#pragma unroll
  for (int u = 0; u < U; ++u) sh.red[s][c][u] = acc[u];
  __syncthreads();

  for (int p = tid; p < 64 * U; p += 256) {
    int cc = p & 63, u = p >> 6;
    int dg = bx * 64 + cc;
    float pre = sh.red[0][cc][u] + sh.red[1][cc][u] + sh.red[2][cc][u] + sh.red[3][cc][u]
              + dpb[dg];
    float dt = fmaxf(pre, 0.f) + log1pf(expf(-fabsf(pre)));   // softplus
    dt_ws[u * DI + dg] = dt;
  }
}

__device__ __forceinline__ void k3b_body(
    int i,
    const float* __restrict__ x_dbl,
    const float* __restrict__ alog, const float* __restrict__ Dp,
    const float* __restrict__ ssm,
    const float* __restrict__ dt_ws,
    const float* __restrict__ c_ws, const float* __restrict__ res_ws,
    float* __restrict__ yr)
{
  const int u = i / DI, d = i - u * DI;
  const float dt = dt_ws[i];
  const float cv = c_ws[i];
  const float rv = res_ws[i];
  const float Dv = Dp[d];
  const float dtc = dt * cv;

  float4 B[4], C[4];
#pragma unroll
  for (int q = 0; q < 4; ++q) {
    B[q] = *(const float4*)&x_dbl[u * XD + RNK + q * 4];
    C[q] = *(const float4*)&x_dbl[u * XD + RNK + DS + q * 4];
  }

  const float* st = ssm + ((size_t)u * DI + d) * DS;
  float y = 0.f;
#pragma unroll
  for (int q = 0; q < 4; ++q) {
    float4 al = *(const float4*)&alog[d * DS + q * 4];
    float4 sv = *(const float4*)&st[q * 4];
    y += (sv.x * __expf(dt * -__expf(al.x)) + dtc * B[q].x) * C[q].x;
    y += (sv.y * __expf(dt * -__expf(al.y)) + dtc * B[q].y) * C[q].y;
    y += (sv.z * __expf(dt * -__expf(al.z)) + dtc * B[q].z) * C[q].z;
    y += (sv.w * __expf(dt * -__expf(al.w)) + dtc * B[q].w) * C[q].w;
  }
  y = fmaf(Dv, cv, y);
  yr[i] = y * rv;
}

// ---------------------------------------------------------------------------
// Fused middle chain (cooperative): conv+silu -> x_proj -> dt -> ssm.
// grid 640 x 256; 3 grid.sync()s.
// ---------------------------------------------------------------------------
__global__ __launch_bounds__(256) void fused_mid(
    const unsigned short* part,
    const float* cs1, const float* cs2, const float* cs3,
    const float* cw,  const float* cb,
    const float* xpw, const float* dpw, const float* dpb,
    const float* alog, const float* Dp, const float* ssm,
    float* c_ws, float* res_ws, float* x_dbl, float* dt_ws, float* yr)
{
  cg::grid_group grid = cg::this_grid();
  __shared__ MidSh sh;
  const int bid = blockIdx.x, tid = threadIdx.x;
  const int t = bid * 256 + tid;

  // phase 1: conv + silu (2 elems/thread over first 320 blocks' worth) + zero x_dbl
  if (t < U * DI / 2)
    k2a_body(t, part, cs1, cs2, cs3, cw, cb, c_ws, res_ws);
  if (t < U * XD / 2)
    *(float2*)&x_dbl[2 * t] = make_float2(0.f, 0.f);
  grid.sync();

  // phase 2: x_proj (192 blocks)
  if (bid < 192)
    k2b_body(sh, bid % 3, bid / 3, tid, c_ws, xpw, x_dbl);
  grid.sync();

  // phase 3: dt (80 blocks)
  if (bid < 80)
    k3a_body(sh, bid, tid, x_dbl, dpw, dpb, dt_ws);
  grid.sync();

  // phase 4: ssm elementwise (all 640 blocks, 1 elem/thread)
  k3b_body(t, x_dbl, alog, Dp, ssm, dt_ws, c_ws, res_ws, yr);
}

// ---------------------------------------------------------------------------
// Fallback separate kernels (same bodies) in case cooperative enqueue fails.
// ---------------------------------------------------------------------------
__global__ __launch_bounds__(256) void k2a_kernel(
    const unsigned short* __restrict__ part,
    const float* __restrict__ cs1, const float* __restrict__ cs2,
    const float* __restrict__ cs3,
    const float* __restrict__ cw,  const float* __restrict__ cb,
    float* __restrict__ c_ws, float* __restrict__ res_ws)
{
  k2a_body(blockIdx.x * 256 + threadIdx.x, part, cs1, cs2, cs3, cw, cb, c_ws, res_ws);
}
__global__ __launch_bounds__(256) void k2b_kernel(
    const float* __restrict__ c_ws, const float* __restrict__ xpw,
    float* __restrict__ x_dbl)
{
  __shared__ MidSh sh;
  k2b_body(sh, blockIdx.x, blockIdx.y, threadIdx.x, c_ws, xpw, x_dbl);
}
__global__ __launch_bounds__(256) void k3a_kernel(
    const float* __restrict__ x_dbl,
    const float* __restrict__ dpw, const float* __restrict__ dpb,
    float* __restrict__ dt_ws)
{
  __shared__ MidSh sh;
  k3a_body(sh, blockIdx.x, threadIdx.x, x_dbl, dpw, dpb, dt_ws);
}
__global__ __launch_bounds__(256) void k3b_kernel(
    const float* __restrict__ x_dbl,
    const float* __restrict__ alog, const float* __restrict__ Dp,
    const float* __restrict__ ssm, const float* __restrict__ dt_ws,
    const float* __restrict__ c_ws, const float* __restrict__ res_ws,
    float* __restrict__ yr)
{
  k3b_body(blockIdx.x * 256 + threadIdx.x, x_dbl, alog, Dp, ssm, dt_ws, c_ws, res_ws, yr);
}

// ---------------------------------------------------------------------------
// K5: out = sum of KC4 bf16 K4 partials.  2 elems/thread.  grid 160.
// ---------------------------------------------------------------------------
__global__ __launch_bounds__(256) void k5_reduce(
    const unsigned short* __restrict__ part4,
    float* __restrict__ out)
{
  const int t = blockIdx.x * 256 + threadIdx.x;   // [0, U*DM/2)
  const int i = 2 * t;
  const int u = i / DM, d = i - u * DM;
  float v0 = 0.f, v1 = 0.f;
#pragma unroll 8
  for (int kc = 0; kc < KC4; ++kc) {
    unsigned int a = *(const unsigned int*)&part4[((size_t)kc * U + u) * DM + d];
    v0 += bf2f(a & 0xffffu);
    v1 += bf2f(a >> 16);
  }
  *(float2*)&out[i] = make_float2(v0, v1);
}

// ---------------------------------------------------------------------------
extern "C" void kernel_launch(void* const* d_in, const int* in_sizes, int n_in,
                              void* d_out, int out_size, void* d_ws, size_t ws_size,
                              hipStream_t stream)
{
  const float* x    = (const float*)d_in[0];
  const float* wssm = (const float*)d_in[1];
  const float* wmlp = (const float*)d_in[2];
  const float* wout = (const float*)d_in[3];
  const float* cw   = (const float*)d_in[4];
  const float* cb   = (const float*)d_in[5];
  const float* cs1  = (const float*)d_in[6];
  const float* cs2  = (const float*)d_in[7];
  const float* cs3  = (const float*)d_in[8];
  const float* xpw  = (const float*)d_in[9];
  const float* dpw  = (const float*)d_in[10];
  const float* dpb  = (const float*)d_in[11];
  const float* alog = (const float*)d_in[12];
  const float* Dp   = (const float*)d_in[13];
  const float* ssm  = (const float*)d_in[14];
  float* out = (float*)d_out;

  unsigned short* partb = (unsigned short*)d_ws;    // 2*KC1*32*DI == KC4*32*DM
  float* c_ws   = (float*)(partb + (size_t)2 * KC1 * U * DI);
  float* res_ws = c_ws   + (size_t)U * DI;
  float* dt_ws  = res_ws + (size_t)U * DI;
  float* yrb    = dt_ws  + (size_t)U * DI;
  float* x_dbl  = yrb    + (size_t)U * DI;          // 6144 floats

  // K1: xs/res = xb @ {w_in_ssm, w_in_mlp}. grid (5120/256, 2560/128, 2) = 800
  skinny_dma<DI, 128><<<dim3(20, KC1, 2), 256, 0, stream>>>(x, DM, wssm, wmlp, partb);

  // fused middle chain (cooperative); fallback to separate kernels on failure
  {
    const unsigned short* part_c = partb;
    void* args[] = {
      (void*)&part_c, (void*)&cs1, (void*)&cs2, (void*)&cs3,
      (void*)&cw, (void*)&cb, (void*)&xpw, (void*)&dpw, (void*)&dpb,
      (void*)&alog, (void*)&Dp, (void*)&ssm,
      (void*)&c_ws, (void*)&res_ws, (void*)&x_dbl, (void*)&dt_ws, (void*)&yrb
    };
    hipError_t err = hipLaunchCooperativeKernel(
        (const void*)fused_mid, dim3(640), dim3(256), args, 0, stream);
    if (err != hipSuccess) {
      (void)hipMemsetAsync(x_dbl, 0, (size_t)U * XD * sizeof(float), stream);
      k2a_kernel<<<320, 256, 0, stream>>>(partb, cs1, cs2, cs3, cw, cb, c_ws, res_ws);
      k2b_kernel<<<dim3(3, 64), 256, 0, stream>>>(c_ws, xpw, x_dbl);
      k3a_kernel<<<80, 256, 0, stream>>>(x_dbl, dpw, dpb, dt_ws);
      k3b_kernel<<<640, 256, 0, stream>>>(x_dbl, alog, Dp, ssm, dt_ws, c_ws, res_ws, yrb);
    }
  }

  // K4: out_part = yr @ w_out. grid (2560/256, 5120/64, 1) = 800
  skinny_dma<DM, 64><<<dim3(10, KC4, 1), 256, 0, stream>>>(yrb, DI, wout, wout, partb);
  k5_reduce<<<160, 256, 0, stream>>>(partb, out);
}

// Round 12
// 77.478 us; speedup vs baseline: 3.8465x; 3.8465x over previous
//
#include <hip/hip_runtime.h>
#include <hip/hip_bf16.h>
#include <cstdint>
#include <cstddef>

#define U   32
#define DM  2560
#define DI  5120
#define DS  16
#define RNK 160
#define XD  192   // RNK + 2*DS
#define KC1 8     // K1 k-slices (SLAB 320)
#define KC4 32    // K4 k-slices (SLAB 160)

typedef __attribute__((ext_vector_type(8)))  short bf16x8;
typedef __attribute__((ext_vector_type(16))) float f32x16;

__device__ __forceinline__ unsigned int pkbf(float a, float b) {
  __hip_bfloat162 h = __float22bfloat162_rn(make_float2(a, b));
  union { __hip_bfloat162 h; unsigned int u; } v; v.h = h; return v.u;
}
__device__ __forceinline__ unsigned short f2bfu(float f) {
  __hip_bfloat16 h = __float2bfloat16(f);
  union { __hip_bfloat16 h; unsigned short u; } v; v.h = h; return v.u;
}
__device__ __forceinline__ float bf2f(unsigned int s) {
  union { float f; unsigned int u; } v; v.u = s << 16; return v.f;
}

// async global->LDS DMA, 16B per lane; lds dest = wave-uniform base + lane*16
__device__ __forceinline__ void gl_lds16(const float* g, float* l) {
  __builtin_amdgcn_global_load_lds(
      (const __attribute__((address_space(1))) unsigned int*)g,
      (__attribute__((address_space(3))) unsigned int*)l,
      16, 0, 0);
}

// ---------------------------------------------------------------------------
// MFMA skinny GEMM (round-9 v6, the measured-best config):
// bf16 partials part[z][kcb][32][LDW] = A[32 x SLAB] @ W[k0..k0+SLAB][LDW].
// block 256 = 4 waves, 256 cols; SLAB rows in 16-row double-buffered steps.
// Stage: 16x global_load_lds dwordx4 (one contiguous 1KB row segment each).
// ---------------------------------------------------------------------------
template<int LDW, int SLAB>
__global__ __launch_bounds__(256, 3) void skinny_dma(
    const float* __restrict__ A, int lda,
    const float* __restrict__ W0, const float* __restrict__ W1,
    unsigned short* __restrict__ part)
{
  constexpr int NS = SLAB / 16;
  __shared__ float        wbuf[2][16][256];   // 32 KB fp32 W tiles (dbuf)
  __shared__ unsigned int albuf[NS][64][4];   // A frags bf16, 1KB per k-step

  const int tid  = threadIdx.x;
  const int lane = tid & 63, w = tid >> 6;
  const int kcb  = blockIdx.y, z = blockIdx.z;
  const int k0   = kcb * SLAB;
  const float* __restrict__ W = z ? W1 : W0;
  const int col0 = blockIdx.x * 256;

  // ---- stage A panel [32][SLAB] -> bf16 MFMA-A fragment order (once)
  for (int i = tid; i < U * (SLAB / 2); i += 256) {
    const int u  = i / (SLAB / 2);
    const int kp = i - u * (SLAB / 2);
    const int k  = 2 * kp;
    const float2 v = *(const float2*)&A[(size_t)u * lda + k0 + k];
    albuf[k >> 4][u + U * ((k >> 3) & 1)][(k >> 1) & 3] = pkbf(v.x, v.y);
  }

  const int cl = lane & 31, half = lane >> 5;

  // prologue: stage step 0 into buf 0 (wave w stages rows w*4 .. w*4+3)
  {
    const float* src = W + ((size_t)k0 + w * 4) * LDW + col0 + lane * 4;
#pragma unroll
    for (int i = 0; i < 4; ++i)
      gl_lds16(src + (size_t)i * LDW, &wbuf[0][w * 4 + i][0]);
  }

  f32x16 acc0{}, acc1{};

  for (int s = 0; s < NS; ++s) {
    const int buf = s & 1;
    if (s + 1 < NS) {     // stage next step into other buffer
      const float* src = W + ((size_t)k0 + (s + 1) * 16 + w * 4) * LDW
                         + col0 + lane * 4;
#pragma unroll
      for (int i = 0; i < 4; ++i)
        gl_lds16(src + (size_t)i * LDW, &wbuf[buf ^ 1][w * 4 + i][0]);
    }
    __syncthreads();      // drains vmcnt: step-s tile complete

    // consume buf: wave w computes cols w*64 .. w*64+63 (2 frags)
    bf16x8 af = *(const bf16x8*)&albuf[s][lane][0];
#pragma unroll
    for (int f = 0; f < 2; ++f) {
      const int col = w * 64 + f * 32 + cl;
      float r0 = wbuf[buf][half * 8 + 0][col];
      float r1 = wbuf[buf][half * 8 + 1][col];
      float r2 = wbuf[buf][half * 8 + 2][col];
      float r3 = wbuf[buf][half * 8 + 3][col];
      float r4 = wbuf[buf][half * 8 + 4][col];
      float r5 = wbuf[buf][half * 8 + 5][col];
      float r6 = wbuf[buf][half * 8 + 6][col];
      float r7 = wbuf[buf][half * 8 + 7][col];
      union { bf16x8 v; unsigned int d[4]; } bu;
      bu.d[0] = pkbf(r0, r1); bu.d[1] = pkbf(r2, r3);
      bu.d[2] = pkbf(r4, r5); bu.d[3] = pkbf(r6, r7);
      if (f == 0) acc0 = __builtin_amdgcn_mfma_f32_32x32x16_bf16(af, bu.v, acc0, 0, 0, 0);
      else        acc1 = __builtin_amdgcn_mfma_f32_32x32x16_bf16(af, bu.v, acc1, 0, 0, 0);
    }
    __syncthreads();      // all waves done reading buf before it is refilled
  }

  // ---- epilogue: D (col=lane&31, row=(r&3)+8*(r>>2)+4*half) -> bf16 partials
  unsigned short* po = part + (size_t)(z * gridDim.y + kcb) * U * LDW + col0;
#pragma unroll
  for (int f = 0; f < 2; ++f) {
    const f32x16& a = f ? acc1 : acc0;
    const int gc = w * 64 + f * 32 + cl;
#pragma unroll
    for (int r = 0; r < 16; ++r) {
      const int m = (r & 3) + 8 * (r >> 2) + 4 * half;
      po[(size_t)m * LDW + gc] = f2bfu(a[r]);
    }
  }
}

// ---------------------------------------------------------------------------
// K2a: reduce K1 bf16 partials (KC1 per z) + conv + silu; also zeroes x_dbl.
// 2 elems/thread.  grid 320, block 256.
// ---------------------------------------------------------------------------
__global__ __launch_bounds__(256) void k2a_convsilu(
    const unsigned short* __restrict__ part,
    const float* __restrict__ cs1, const float* __restrict__ cs2,
    const float* __restrict__ cs3,
    const float* __restrict__ cw,  const float* __restrict__ cb,
    float* __restrict__ c_ws, float* __restrict__ res_ws,
    float* __restrict__ x_dbl)
{
  const int t = blockIdx.x * 256 + threadIdx.x;   // [0, U*DI/2)
  if (t < U * XD / 2) *(float2*)&x_dbl[2 * t] = make_float2(0.f, 0.f);

  const int i = 2 * t;
  const int u = i / DI, d = i - u * DI;
  float xs0 = 0.f, xs1 = 0.f, rs0 = 0.f, rs1 = 0.f;
#pragma unroll
  for (int kc = 0; kc < KC1; ++kc) {
    unsigned int a = *(const unsigned int*)&part[((size_t)kc * U + u) * DI + d];
    unsigned int b = *(const unsigned int*)&part[((size_t)(KC1 + kc) * U + u) * DI + d];
    xs0 += bf2f(a & 0xffffu); xs1 += bf2f(a >> 16);
    rs0 += bf2f(b & 0xffffu); rs1 += bf2f(b >> 16);
  }
  const float2 s1 = *(const float2*)&cs1[i];
  const float2 s2 = *(const float2*)&cs2[i];
  const float2 s3 = *(const float2*)&cs3[i];
  const float2 w0 = *(const float2*)&cw[d];
  const float2 w1 = *(const float2*)&cw[DI + d];
  const float2 w2 = *(const float2*)&cw[2 * DI + d];
  const float2 w3 = *(const float2*)&cw[3 * DI + d];
  const float2 bb = *(const float2*)&cb[d];
  float c0 = s1.x * w0.x + s2.x * w1.x + s3.x * w2.x + xs0 * w3.x + bb.x;
  float c1 = s1.y * w0.y + s2.y * w1.y + s3.y * w2.y + xs1 * w3.y + bb.y;
  c0 = c0 / (1.f + __expf(-c0));
  c1 = c1 / (1.f + __expf(-c1));
  *(float2*)&c_ws[i]   = make_float2(c0, c1);
  *(float2*)&res_ws[i] = make_float2(rs0, rs1);
}

// ---------------------------------------------------------------------------
// K2b: x_dbl = c @ x_proj_w (32x5120 @ 5120x192).  grid (3, 64), block 256.
// K-chunk 80; wave owns 20-row slice; LDS reduce; atomics (64/addr).
// ---------------------------------------------------------------------------
__global__ __launch_bounds__(256) void k2b_xproj(
    const float* __restrict__ c_ws,
    const float* __restrict__ xpw,
    float* __restrict__ x_dbl)
{
  __shared__ union { float ct[U][80]; float red[4][64][33]; } sh;
  const int k0 = blockIdx.y * 80;

  for (int i4 = threadIdx.x; i4 < U * 20; i4 += 256) {
    int u = i4 / 20, k4 = i4 - u * 20;
    *(float4*)&sh.ct[u][k4 * 4] = *(const float4*)&c_ws[u * DI + k0 + k4 * 4];
  }
  __syncthreads();

  const int c = threadIdx.x & 63, s = threadIdx.x >> 6;
  const int col = blockIdx.x * 64 + c;              // 0..191
  const float* Wp = xpw + (size_t)(k0 + s * 20) * XD + col;

  float acc[U];
#pragma unroll
  for (int u = 0; u < U; ++u) acc[u] = 0.f;

  for (int kk = 0; kk < 20; kk += 4) {
    float w0 = Wp[(size_t)(kk + 0) * XD];
    float w1 = Wp[(size_t)(kk + 1) * XD];
    float w2 = Wp[(size_t)(kk + 2) * XD];
    float w3 = Wp[(size_t)(kk + 3) * XD];
#pragma unroll
    for (int u = 0; u < U; ++u) {
      float4 cv = *(const float4*)&sh.ct[u][s * 20 + kk];
      acc[u] = fmaf(cv.x, w0, acc[u]);
      acc[u] = fmaf(cv.y, w1, acc[u]);
      acc[u] = fmaf(cv.z, w2, acc[u]);
      acc[u] = fmaf(cv.w, w3, acc[u]);
    }
  }

  __syncthreads();
#pragma unroll
  for (int u = 0; u < U; ++u) sh.red[s][c][u] = acc[u];
  __syncthreads();

  for (int p = threadIdx.x; p < 64 * U; p += 256) {
    int cc = p & 63, u = p >> 6;
    float v = sh.red[0][cc][u] + sh.red[1][cc][u] + sh.red[2][cc][u] + sh.red[3][cc][u];
    atomicAdd(&x_dbl[u * XD + blockIdx.x * 64 + cc], v);
  }
}

// ---------------------------------------------------------------------------
// K3: FUSED dt + SSM.  grid 80, block 256.  Block bx owns d-cols bx*64..+63.
// Phase A (k3a): dt = softplus(x_dbl[:,:160] @ dpw + b) -> LDS dtl[32][64].
// Phase B (k3b): ssm update + einsum + D*c, yr = y*res for the 32x64 tile.
// ---------------------------------------------------------------------------
__global__ __launch_bounds__(256) void k3_fused(
    const float* __restrict__ x_dbl,
    const float* __restrict__ dpw, const float* __restrict__ dpb,
    const float* __restrict__ alog, const float* __restrict__ Dp,
    const float* __restrict__ ssm,
    const float* __restrict__ c_ws, const float* __restrict__ res_ws,
    float* __restrict__ yr)
{
  __shared__ union { float xt[U][160]; float red[4][64][33]; } sh;
  __shared__ float dtl[U][64];
  __shared__ float bc[U][32];        // B (0..15) and C (16..31) per user

  const int tid = threadIdx.x, bx = blockIdx.x;

  // stage dt-rank panel + B/C
  for (int i4 = tid; i4 < U * 40; i4 += 256) {
    int u = i4 / 40, r4 = i4 - u * 40;
    *(float4*)&sh.xt[u][r4 * 4] = *(const float4*)&x_dbl[u * XD + r4 * 4];
  }
  for (int i = tid; i < U * 32; i += 256) {
    int u = i >> 5, j = i & 31;
    bc[u][j] = x_dbl[u * XD + RNK + j];
  }
  __syncthreads();

  const int c = tid & 63, s = tid >> 6;
  const int d = bx * 64 + c;
  const float* Wp = dpw + (size_t)(s * 40) * DI + d;

  float acc[U];
#pragma unroll
  for (int u = 0; u < U; ++u) acc[u] = 0.f;

  for (int rr = 0; rr < 40; rr += 4) {
    float w0 = Wp[(size_t)(rr + 0) * DI];
    float w1 = Wp[(size_t)(rr + 1) * DI];
    float w2 = Wp[(size_t)(rr + 2) * DI];
    float w3 = Wp[(size_t)(rr + 3) * DI];
#pragma unroll
    for (int u = 0; u < U; ++u) {
      float4 xv = *(const float4*)&sh.xt[u][s * 40 + rr];
      acc[u] = fmaf(xv.x, w0, acc[u]);
      acc[u] = fmaf(xv.y, w1, acc[u]);
      acc[u] = fmaf(xv.z, w2, acc[u]);
      acc[u] = fmaf(xv.w, w3, acc[u]);
    }
  }

  __syncthreads();
#pragma unroll
  for (int u = 0; u < U; ++u) sh.red[s][c][u] = acc[u];
  __syncthreads();

  for (int p = tid; p < 64 * U; p += 256) {
    int cc = p & 63, u = p >> 6;
    float pre = sh.red[0][cc][u] + sh.red[1][cc][u] + sh.red[2][cc][u] + sh.red[3][cc][u]
              + dpb[bx * 64 + cc];
    dtl[u][cc] = fmaxf(pre, 0.f) + log1pf(expf(-fabsf(pre)));   // softplus
  }
  __syncthreads();

  // phase B: per wave-iteration u is uniform, lanes cover cc 0..63 (coalesced)
  for (int p = tid; p < 64 * U; p += 256) {
    const int cc = p & 63, u = p >> 6;
    const int dg = bx * 64 + cc;
    const int i  = u * DI + dg;
    const float dt = dtl[u][cc];
    const float cv = c_ws[i];
    const float rv = res_ws[i];
    const float Dv = Dp[dg];
    const float dtc = dt * cv;

    const float* st = ssm + ((size_t)u * DI + dg) * DS;
    float y = 0.f;
#pragma unroll
    for (int q = 0; q < 4; ++q) {
      float4 al = *(const float4*)&alog[dg * DS + q * 4];
      float4 sv = *(const float4*)&st[q * 4];
      y += (sv.x * __expf(dt * -__expf(al.x)) + dtc * bc[u][q * 4 + 0])      * bc[u][16 + q * 4 + 0];
      y += (sv.y * __expf(dt * -__expf(al.y)) + dtc * bc[u][q * 4 + 1])      * bc[u][16 + q * 4 + 1];
      y += (sv.z * __expf(dt * -__expf(al.z)) + dtc * bc[u][q * 4 + 2])      * bc[u][16 + q * 4 + 2];
      y += (sv.w * __expf(dt * -__expf(al.w)) + dtc * bc[u][q * 4 + 3])      * bc[u][16 + q * 4 + 3];
    }
    y = fmaf(Dv, cv, y);
    yr[i] = y * rv;
  }
}

// ---------------------------------------------------------------------------
// K5: out = sum of KC4 bf16 K4 partials.  2 elems/thread.  grid 160.
// ---------------------------------------------------------------------------
__global__ __launch_bounds__(256) void k5_reduce(
    const unsigned short* __restrict__ part4,
    float* __restrict__ out)
{
  const int t = blockIdx.x * 256 + threadIdx.x;   // [0, U*DM/2)
  const int i = 2 * t;
  const int u = i / DM, d = i - u * DM;
  float v0 = 0.f, v1 = 0.f;
#pragma unroll 8
  for (int kc = 0; kc < KC4; ++kc) {
    unsigned int a = *(const unsigned int*)&part4[((size_t)kc * U + u) * DM + d];
    v0 += bf2f(a & 0xffffu);
    v1 += bf2f(a >> 16);
  }
  *(float2*)&out[i] = make_float2(v0, v1);
}

// ---------------------------------------------------------------------------
extern "C" void kernel_launch(void* const* d_in, const int* in_sizes, int n_in,
                              void* d_out, int out_size, void* d_ws, size_t ws_size,
                              hipStream_t stream)
{
  const float* x    = (const float*)d_in[0];
  const float* wssm = (const float*)d_in[1];
  const float* wmlp = (const float*)d_in[2];
  const float* wout = (const float*)d_in[3];
  const float* cw   = (const float*)d_in[4];
  const float* cb   = (const float*)d_in[5];
  const float* cs1  = (const float*)d_in[6];
  const float* cs2  = (const float*)d_in[7];
  const float* cs3  = (const float*)d_in[8];
  const float* xpw  = (const float*)d_in[9];
  const float* dpw  = (const float*)d_in[10];
  const float* dpb  = (const float*)d_in[11];
  const float* alog = (const float*)d_in[12];
  const float* Dp   = (const float*)d_in[13];
  const float* ssm  = (const float*)d_in[14];
  float* out = (float*)d_out;

  // workspace: bf16 partials (aliased K1/K4: both 2,621,440 ushorts), fp32 after
  unsigned short* partb = (unsigned short*)d_ws;    // 2*KC1*32*DI == KC4*32*DM
  float* c_ws   = (float*)(partb + (size_t)2 * KC1 * U * DI);
  float* res_ws = c_ws   + (size_t)U * DI;
  float* yrb    = res_ws + (size_t)U * DI;
  float* x_dbl  = yrb    + (size_t)U * DI;          // 6144 floats

  // K1: xs/res = xb @ {w_in_ssm, w_in_mlp}. grid (5120/256, 2560/320, 2) = 320
  skinny_dma<DI, 320><<<dim3(20, KC1, 2), 256, 0, stream>>>(x, DM, wssm, wmlp, partb);
  k2a_convsilu<<<320, 256, 0, stream>>>(partb, cs1, cs2, cs3, cw, cb, c_ws, res_ws, x_dbl);
  k2b_xproj<<<dim3(3, 64), 256, 0, stream>>>(c_ws, xpw, x_dbl);
  k3_fused<<<80, 256, 0, stream>>>(x_dbl, dpw, dpb, alog, Dp, ssm, c_ws, res_ws, yrb);
  // K4: out_part = yr @ w_out. grid (2560/256, 5120/160, 1) = 320
  skinny_dma<DM, 160><<<dim3(10, KC4, 1), 256, 0, stream>>>(yrb, DI, wout, wout, partb);
  k5_reduce<<<160, 256, 0, stream>>>(partb, out);
}